// Round 18
// baseline (224.856 us; speedup 1.0000x reference)
//
#include <hip/hip_runtime.h>

#define NROW 16384
#define ROWI 10246
#define NSLOT 323                 // B slots: 0..319 tiles, 321=D@t0, 322=A@t69
#define BF_U16 ((size_t)NSLOT*128*8)
#define PTAB_ROWS 3438
#define PTAB_F (PTAB_ROWS*64)

typedef unsigned int u32;
typedef unsigned long long u64;
typedef unsigned short u16;
typedef short short8 __attribute__((ext_vector_type(8)));
typedef float f32x4 __attribute__((ext_vector_type(4)));

union AFrag { u32 u[4]; short8 s; };
union BFrag { uint4 v; short8 s; };

// ---------------- prep: B fragment table (bf16, MFMA layout) ----------------
// Frag id = (slot*2 + f)*64 + lane ; elem e: k = t*32 + (lane>>4)*8 + e,
// d = f*16 + (lane&15). Masked to the slot's segment (zeros elsewhere).
__global__ void prep_bf(const float* __restrict__ Wg, const float* __restrict__ Wd,
                        const float* __restrict__ Wa, u16* __restrict__ Bf) {
  int id = blockIdx.x*256 + threadIdx.x;
  if (id >= NSLOT*128) return;
  int lane = id & 63, f = (id >> 6) & 1, slot = id >> 7;
  int t   = (slot == 321) ? 0 : (slot == 322) ? 69 : slot;
  int seg = (slot == 0) ? 0 : (slot <= 69) ? 1 : (slot <= 320) ? 2
            : (slot == 321) ? 1 : 2;                  // 0=G,1=D,2=A
  int clo = (seg == 0) ? 1  : (seg == 1) ? 26   : 2212;
  int chi = (seg == 0) ? 26 : (seg == 1) ? 2212 : 10242;
  int d  = f*16 + (lane & 15);
  int kb = t*32 + (lane >> 4)*8;
  u16 o[8];
  #pragma unroll
  for (int e = 0; e < 8; ++e) {
    int c = kb + e;
    float v = 0.f;
    if (c >= clo && c < chi) {
      if (seg == 0)      v = Wg[d*25   + (c-1)];
      else if (seg == 1) v = Wd[d*2186 + (c-26)];
      else               v = Wa[d*8030 + (c-2212)];
    }
    u32 bits = __float_as_uint(v);                    // RNE float->bf16
    o[e] = (u16)((bits + 0x7FFFu + ((bits >> 16) & 1u)) >> 16);
  }
  uint4 w;
  w.x = (u32)o[0] | ((u32)o[1] << 16);
  w.y = (u32)o[2] | ((u32)o[3] << 16);
  w.z = (u32)o[4] | ((u32)o[5] << 16);
  w.w = (u32)o[6] | ((u32)o[7] << 16);
  *(uint4*)&Bf[(size_t)id*8] = w;
}

// ---------------- prep: folded index-embedding table ----------------
__global__ void prep_p(const float* __restrict__ er, const float* __restrict__ eg,
                       const float* __restrict__ ea, const float* __restrict__ eo,
                       const float* __restrict__ ez, const float* __restrict__ W1,
                       float* __restrict__ P) {
  int id = blockIdx.x*256 + threadIdx.x;
  if (id >= PTAB_F) return;
  int r = id >> 6, o = id & 63;
  const float* emb; int woff;
  if (r < 6)       { emb = er + r*32;       woff = 0;   }
  else if (r < 8)  { emb = eg + (r-6)*32;   woff = 128; }
  else if (r < 15) { emb = ea + (r-8)*32;   woff = 160; }
  else if (r < 36) { emb = eo + (r-15)*32;  woff = 192; }
  else             { emb = ez + (r-36)*32;  woff = 224; }
  const float* w = W1 + o*256 + woff;
  float s = 0.f;
  #pragma unroll
  for (int c2 = 0; c2 < 32; ++c2) s += emb[c2]*w[c2];
  P[id] = s;
}

// ---------------- fully fused: pack + MFMA + mean + MLP ----------------
// Block = 256 thr (4 waves) = 32 rows (r17-validated, 218 us). ONE change:
// phase-1 streams TWO rows interleaved (ballot row A while row B's NT loads
// are in flight) -> 32-64 outstanding loads/wave instead of <=32.
__global__ __launch_bounds__(256, 2) void fusedK(
    const int* __restrict__ x, const u16* __restrict__ Bf,
    const float* __restrict__ P, const float* __restrict__ W1,
    const float* __restrict__ b1, const float* __restrict__ W2,
    const float* __restrict__ b2, const float* __restrict__ Wout,
    const float* __restrict__ bout, const float* __restrict__ Wa,
    float* __restrict__ out) {
  __shared__ __align__(16) u32 bitsL[32*324];  // bits; aliased as hL in epilogue
  __shared__ float poutL[4][33][32];           // 0=G(h0),1=D(h0),2=A(h0),3=A(h1)
  __shared__ int   sideL[32][8];
  __shared__ float cCnt[3][32];

  const int lane = threadIdx.x & 63;
  const int wv   = threadIdx.x >> 6;
  const int row0 = blockIdx.x * 32;
  const int r = lane & 15, g = lane >> 4, g8 = g*8;

  // ---- phase 1: 8 rows per wave, processed in interleaved pairs, NT loads --
#define LD32(V, BASE, GG) do { _Pragma("unroll")                               \
    for (int k_ = 0; k_ < 32; ++k_)                                            \
      V[k_] = __builtin_nontemporal_load((BASE) + (GG)*2048 + k_*64 + lane); } while (0)
#define BST(V, RL, GG) do { u32 keep = 0;                                      \
    _Pragma("unroll")                                                          \
    for (int k_ = 0; k_ < 32; ++k_) {                                          \
      const u64 b_ = __ballot(V[k_] != 0);                                     \
      keep = (lane == 2*k_)     ? (u32)b_        : keep;                       \
      keep = (lane == 2*k_ + 1) ? (u32)(b_>>32)  : keep;                       \
    }                                                                          \
    bitsL[(RL)*324 + (GG)*64 + lane] = keep; } while (0)

  for (int i8 = 0; i8 < 8; i8 += 2) {
    const int rA = wv*8 + i8, rB = rA + 1;
    const int* baseA = x + (size_t)(row0 + rA)*ROWI;
    const int* baseB = x + (size_t)(row0 + rB)*ROWI;
    int vA[32], vB[32];
    LD32(vA, baseA, 0);
    #pragma unroll
    for (int gg = 0; gg < 5; ++gg) {
      LD32(vB, baseB, gg);          // B's loads fly while balloting A
      BST(vA, rA, gg);
      if (gg < 4) LD32(vA, baseA, gg+1);  // A's next loads fly while balloting B
      BST(vB, rB, gg);
    }
  }
#undef LD32
#undef BST
  {
    const int i2 = lane >> 3, j = lane & 7;
    if (j < 7) {
      const int* bp = x + (size_t)(row0 + wv*8 + i2)*ROWI;
      sideL[wv*8 + i2][j] = (j == 0) ? bp[0] : bp[10239 + j];
    }
  }
  __syncthreads();

  // ---- phase 2 (r11/r16 verbatim) ----
  const int s16 = (wv & 1) * 16;
  const bool h0 = (wv >> 1) == 0;
  const int tb = h0 ? 0 : 160;
  const int tmax = tb + 159;
  const u32* brow = &bitsL[(s16 + r)*324];
  const uint4* pB = (const uint4*)Bf;          // frag id

  f32x4 z = {0.f,0.f,0.f,0.f};
  f32x4 G0=z,G1=z,D0=z,D1=z,A0=z,A1=z;
  int cG=0,cD=0,cA=0;

  uint4 B00 = pB[((tb+0)*2)*64 + lane], B01 = pB[((tb+0)*2+1)*64 + lane];
  uint4 B10 = pB[((tb+1)*2)*64 + lane], B11 = pB[((tb+1)*2+1)*64 + lane];
  uint4 B20 = pB[((tb+2)*2)*64 + lane], B21 = pB[((tb+2)*2+1)*64 + lane];
  uint4 B30 = pB[((tb+3)*2)*64 + lane], B31 = pB[((tb+3)*2+1)*64 + lane];

#define MFMA_(AF, B, ACC) __builtin_amdgcn_mfma_f32_16x16x32_bf16((AF).s, (B).s, ACC, 0,0,0)

#define TILEW(J, T) do {                                                       \
    const int t = (T);                                                         \
    const u32 byte = (W4##J >> g8) & 0xFFu;                                    \
    AFrag af;                                                                  \
    af.u[0] = __umul24((byte & 1u)    + (((byte>>1)&1u)<<16), 0x3F80u);        \
    af.u[1] = __umul24(((byte>>2)&1u) + (((byte>>3)&1u)<<16), 0x3F80u);        \
    af.u[2] = __umul24(((byte>>4)&1u) + (((byte>>5)&1u)<<16), 0x3F80u);        \
    af.u[3] = __umul24(((byte>>6)&1u) + (((byte>>7)&1u)<<16), 0x3F80u);        \
    BFrag b0, b1; b0.v = B##J##0; b1.v = B##J##1;                              \
    if (!h0) {                                                                 \
      A0 = MFMA_(af,b0,A0); A1 = MFMA_(af,b1,A1); cA += __popc(byte);          \
    } else if (t == 0) {                                                       \
      G0 = MFMA_(af,b0,G0); G1 = MFMA_(af,b1,G1);                              \
      BFrag e0,e1; e0.v = pB[(321*2)*64 + lane]; e1.v = pB[(321*2+1)*64 + lane]; \
      D0 = MFMA_(af,e0,D0); D1 = MFMA_(af,e1,D1);                              \
      _Pragma("unroll")                                                        \
      for (int jj = 0; jj < 4; ++jj) {                                         \
        const int c0 = g8 + 2*jj, c1 = c0 + 1;                                 \
        const int u0 = (byte>>(2*jj))&1, u1 = (byte>>(2*jj+1))&1;              \
        if (c0 >= 1 && c0 < 26) cG += u0; else if (c0 >= 26) cD += u0;         \
        if (c1 < 26) cG += u1; else cD += u1;                                  \
      }                                                                        \
    } else if (t == 69) {                                                      \
      D0 = MFMA_(af,b0,D0); D1 = MFMA_(af,b1,D1);                              \
      BFrag e0,e1; e0.v = pB[(322*2)*64 + lane]; e1.v = pB[(322*2+1)*64 + lane]; \
      A0 = MFMA_(af,e0,A0); A1 = MFMA_(af,e1,A1);                              \
      _Pragma("unroll")                                                        \
      for (int jj = 0; jj < 4; ++jj) {                                         \
        const int s01 = ((byte>>(2*jj))&1) + ((byte>>(2*jj+1))&1);             \
        if (jj < 2) { if (g == 0) cD += s01; else cA += s01; }                 \
        else cA += s01;                                                        \
      }                                                                        \
    } else if (t < 69) {                                                       \
      D0 = MFMA_(af,b0,D0); D1 = MFMA_(af,b1,D1); cD += __popc(byte);          \
    } else {                                                                   \
      A0 = MFMA_(af,b0,A0); A1 = MFMA_(af,b1,A1); cA += __popc(byte);          \
    }                                                                          \
    int tn = t + 4; if (tn > tmax) tn = tmax;                                  \
    B##J##0 = pB[(tn*2)*64 + lane]; B##J##1 = pB[(tn*2+1)*64 + lane];          \
  } while (0)

  for (int i = 0; i < 40; ++i) {
    const int t0 = tb + 4*i;
    const uint4 W4u = *(const uint4*)&brow[t0];    // ds_read_b128: 4 tiles
    const u32 W40 = W4u.x, W41 = W4u.y, W42 = W4u.z, W43 = W4u.w;
    TILEW(0, t0); TILEW(1, t0+1); TILEW(2, t0+2); TILEW(3, t0+3);
  }
#undef TILEW

  cG += __shfl_xor(cG,16); cG += __shfl_xor(cG,32);
  cD += __shfl_xor(cD,16); cD += __shfl_xor(cD,32);
  cA += __shfl_xor(cA,16); cA += __shfl_xor(cA,32);

#define STOF(ACC0, ACC1, SLOT) do {                                            \
    *(f32x4*)&poutL[SLOT][r][s16 + 4*g]    = ACC0;                             \
    *(f32x4*)&poutL[SLOT][16+r][s16 + 4*g] = ACC1; } while (0)

  if (h0) {
    STOF(G0,G1,0); STOF(D0,D1,1); STOF(A0,A1,2);
    if (lane < 16) {
      poutL[0][32][s16+lane] = (float)cG;
      poutL[1][32][s16+lane] = (float)cD;
      poutL[2][32][s16+lane] = (float)cA;
    }
  } else {
    STOF(A0,A1,3);
    if (lane < 16) poutL[3][32][s16+lane] = (float)cA;
  }
#undef STOF
  __syncthreads();

  // ---- epilogue A: merged counts (with actor tail cols 10240/10241) ----
  if (threadIdx.x < 96) {
    const int seg = threadIdx.x >> 5, row = threadIdx.x & 31;
    float c = poutL[seg][32][row];
    if (seg == 2)
      c += poutL[3][32][row] + (float)sideL[row][1] + (float)sideL[row][2];
    cCnt[seg][row] = c;
  }
  __syncthreads();

  // ---- epilogue B: merge means + tail + divide (in place, slots 0..2) ----
  for (int id = threadIdx.x; id < 3*32*32; id += 256) {
    const int seg = id >> 10;
    const int rem = id & 1023;
    const int d = rem >> 5, row = rem & 31;
    float v = poutL[seg][d][row];
    if (seg == 2) {
      v += poutL[3][d][row];
      v += (float)sideL[row][1] * Wa[d*8030 + 8028]
         + (float)sideL[row][2] * Wa[d*8030 + 8029];
    }
    poutL[seg][d][row] = v / cCnt[seg][row];
  }
  __syncthreads();

  // ---- epilogue C: h1 (8 threads per row, 8 outputs each) ----
  float* hL = (float*)bitsL;                    // [32][64]; bits are dead
  {
    const int row = threadIdx.x >> 3, p = threadIdx.x & 7;
    const int* sd = sideL[row];
    const float* Pr = P + (size_t)sd[0]*64        + p*8;
    const float* Pg = P + (size_t)(6  + sd[3])*64 + p*8;
    const float* Pa = P + (size_t)(8  + sd[4])*64 + p*8;
    const float* Po = P + (size_t)(15 + sd[5])*64 + p*8;
    const float* Pz = P + (size_t)(36 + sd[6])*64 + p*8;
    #pragma unroll
    for (int oo = 0; oo < 8; ++oo) {
      const int o = p*8 + oo;
      float a = b1[o] + ((Pr[oo] + Pg[oo]) + (Pa[oo] + Po[oo])) + Pz[oo];
      const float* w = W1 + o*256;
      #pragma unroll
      for (int d = 0; d < 32; ++d) a = fmaf(poutL[0][d][row], w[32+d], a);
      #pragma unroll
      for (int d = 0; d < 32; ++d) a = fmaf(poutL[1][d][row], w[64+d], a);
      #pragma unroll
      for (int d = 0; d < 32; ++d) a = fmaf(poutL[2][d][row], w[96+d], a);
      hL[row*64 + o] = fmaxf(a, 0.f);
    }
  }
  __syncthreads();

  // ---- epilogue D: h2 + output dot (8 threads per row) ----
  {
    const int row = threadIdx.x >> 3, p = threadIdx.x & 7;
    const float* hr = &hL[row*64];
    float part = 0.f;
    #pragma unroll
    for (int oo = 0; oo < 8; ++oo) {
      const int o2 = p*8 + oo;
      const float* w = W2 + o2*64;
      float acc2 = b2[o2];
      #pragma unroll
      for (int o = 0; o < 64; ++o) acc2 = fmaf(hr[o], w[o], acc2);
      part += fmaxf(acc2, 0.f) * Wout[o2];
    }
    part += __shfl_xor(part, 1);
    part += __shfl_xor(part, 2);
    part += __shfl_xor(part, 4);
    if (p == 0) out[row0 + row] = part + bout[0];
  }
}

// ---------------- launcher ----------------
extern "C" void kernel_launch(void* const* d_in, const int* in_sizes, int n_in,
                              void* d_out, int out_size, void* d_ws, size_t ws_size,
                              hipStream_t stream) {
  (void)in_sizes; (void)n_in; (void)out_size; (void)ws_size;
  const int*   x        = (const int*)  d_in[0];
  const float* emb_rate = (const float*)d_in[1];
  const float* W_genre  = (const float*)d_in[2];
  const float* W_dir    = (const float*)d_in[3];
  const float* W_actor  = (const float*)d_in[4];
  const float* emb_gen  = (const float*)d_in[5];
  const float* emb_age  = (const float*)d_in[6];
  const float* emb_occ  = (const float*)d_in[7];
  const float* emb_area = (const float*)d_in[8];
  const float* W1   = (const float*)d_in[9];
  const float* b1   = (const float*)d_in[10];
  const float* W2   = (const float*)d_in[11];
  const float* b2   = (const float*)d_in[12];
  const float* Wout = (const float*)d_in[13];
  const float* bout = (const float*)d_in[14];
  float* outp = (float*)d_out;

  float* ws = (float*)d_ws;
  u16*   Bf = (u16*)ws;                               // 646 KB, 16B-aligned
  float* P  = (float*)(Bf + BF_U16);

  prep_bf<<<(NSLOT*128 + 255)/256, 256, 0, stream>>>(W_genre, W_dir, W_actor, Bf);
  prep_p<<<(PTAB_F + 255)/256, 256, 0, stream>>>(emb_rate, emb_gen, emb_age, emb_occ,
                                                 emb_area, W1, P);

  fusedK<<<NROW/32, 256, 0, stream>>>(x, Bf, P, W1, b1, W2, b2, Wout, bout,
                                      W_actor, outp);
}

// Round 19
// 219.030 us; speedup vs baseline: 1.0266x; 1.0266x over previous
//
#include <hip/hip_runtime.h>

#define NROW 16384
#define ROWI 10246
#define NSLOT 323                 // B slots: 0..319 tiles, 321=D@t0, 322=A@t69
#define BF_U16 ((size_t)NSLOT*128*8)
#define PTAB_ROWS 3438
#define PTAB_F (PTAB_ROWS*64)

typedef unsigned int u32;
typedef unsigned long long u64;
typedef unsigned short u16;
typedef short short8 __attribute__((ext_vector_type(8)));
typedef float f32x4 __attribute__((ext_vector_type(4)));

union AFrag { u32 u[4]; short8 s; };
union BFrag { uint4 v; short8 s; };

// ---------------- prep: B fragment table (bf16, MFMA layout) ----------------
// Frag id = (slot*2 + f)*64 + lane ; elem e: k = t*32 + (lane>>4)*8 + e,
// d = f*16 + (lane&15). Masked to the slot's segment (zeros elsewhere).
__global__ void prep_bf(const float* __restrict__ Wg, const float* __restrict__ Wd,
                        const float* __restrict__ Wa, u16* __restrict__ Bf) {
  int id = blockIdx.x*256 + threadIdx.x;
  if (id >= NSLOT*128) return;
  int lane = id & 63, f = (id >> 6) & 1, slot = id >> 7;
  int t   = (slot == 321) ? 0 : (slot == 322) ? 69 : slot;
  int seg = (slot == 0) ? 0 : (slot <= 69) ? 1 : (slot <= 320) ? 2
            : (slot == 321) ? 1 : 2;                  // 0=G,1=D,2=A
  int clo = (seg == 0) ? 1  : (seg == 1) ? 26   : 2212;
  int chi = (seg == 0) ? 26 : (seg == 1) ? 2212 : 10242;
  int d  = f*16 + (lane & 15);
  int kb = t*32 + (lane >> 4)*8;
  u16 o[8];
  #pragma unroll
  for (int e = 0; e < 8; ++e) {
    int c = kb + e;
    float v = 0.f;
    if (c >= clo && c < chi) {
      if (seg == 0)      v = Wg[d*25   + (c-1)];
      else if (seg == 1) v = Wd[d*2186 + (c-26)];
      else               v = Wa[d*8030 + (c-2212)];
    }
    u32 bits = __float_as_uint(v);                    // RNE float->bf16
    o[e] = (u16)((bits + 0x7FFFu + ((bits >> 16) & 1u)) >> 16);
  }
  uint4 w;
  w.x = (u32)o[0] | ((u32)o[1] << 16);
  w.y = (u32)o[2] | ((u32)o[3] << 16);
  w.z = (u32)o[4] | ((u32)o[5] << 16);
  w.w = (u32)o[6] | ((u32)o[7] << 16);
  *(uint4*)&Bf[(size_t)id*8] = w;
}

// ---------------- prep: folded index-embedding table ----------------
__global__ void prep_p(const float* __restrict__ er, const float* __restrict__ eg,
                       const float* __restrict__ ea, const float* __restrict__ eo,
                       const float* __restrict__ ez, const float* __restrict__ W1,
                       float* __restrict__ P) {
  int id = blockIdx.x*256 + threadIdx.x;
  if (id >= PTAB_F) return;
  int r = id >> 6, o = id & 63;
  const float* emb; int woff;
  if (r < 6)       { emb = er + r*32;       woff = 0;   }
  else if (r < 8)  { emb = eg + (r-6)*32;   woff = 128; }
  else if (r < 15) { emb = ea + (r-8)*32;   woff = 160; }
  else if (r < 36) { emb = eo + (r-15)*32;  woff = 192; }
  else             { emb = ez + (r-36)*32;  woff = 224; }
  const float* w = W1 + o*256 + woff;
  float s = 0.f;
  #pragma unroll
  for (int c2 = 0; c2 < 32; ++c2) s += emb[c2]*w[c2];
  P[id] = s;
}

// ---------------- fully fused: pack + MFMA + mean + MLP ----------------
// Block = 256 thr (4 waves) = 32 rows (r17-validated, 218 us).
// Phase 1: pack rows -> LDS bits (NT loads + ballot). Phase 2: wave
// (rowset s, K-half h) MFMA. Epilogue: merge, divide, 8-thr/row MLP.
__global__ __launch_bounds__(256, 2) void fusedK(
    const int* __restrict__ x, const u16* __restrict__ Bf,
    const float* __restrict__ P, const float* __restrict__ W1,
    const float* __restrict__ b1, const float* __restrict__ W2,
    const float* __restrict__ b2, const float* __restrict__ Wout,
    const float* __restrict__ bout, const float* __restrict__ Wa,
    float* __restrict__ out) {
  __shared__ __align__(16) u32 bitsL[32*324];  // bits; aliased as hL in epilogue
  __shared__ float poutL[4][33][32];           // 0=G(h0),1=D(h0),2=A(h0),3=A(h1)
  __shared__ int   sideL[32][8];
  __shared__ float cCnt[3][32];

  const int lane = threadIdx.x & 63;
  const int wv   = threadIdx.x >> 6;
  const int row0 = blockIdx.x * 32;
  const int r = lane & 15, g = lane >> 4, g8 = g*8;

  // ---- phase 1: each wave packs 8 rows, 32-deep batches, NT loads ----
  for (int i8 = 0; i8 < 8; ++i8) {
    const int rL = wv*8 + i8;
    const int* base = x + (size_t)(row0 + rL)*ROWI;
    #pragma unroll
    for (int gg = 0; gg < 5; ++gg) {
      int v[32];
      #pragma unroll
      for (int k = 0; k < 32; ++k)
        v[k] = __builtin_nontemporal_load(base + gg*2048 + k*64 + lane);
      u32 keep = 0;
      #pragma unroll
      for (int k = 0; k < 32; ++k) {
        const u64 b = __ballot(v[k] != 0);
        keep = (lane == 2*k)     ? (u32)b         : keep;
        keep = (lane == 2*k + 1) ? (u32)(b >> 32) : keep;
      }
      bitsL[rL*324 + gg*64 + lane] = keep;
    }
  }
  {
    const int i2 = lane >> 3, j = lane & 7;
    if (j < 7) {
      const int* bp = x + (size_t)(row0 + wv*8 + i2)*ROWI;
      sideL[wv*8 + i2][j] = (j == 0) ? bp[0] : bp[10239 + j];
    }
  }
  __syncthreads();

  // ---- phase 2 (r11/r16 verbatim) ----
  const int s16 = (wv & 1) * 16;
  const bool h0 = (wv >> 1) == 0;
  const int tb = h0 ? 0 : 160;
  const int tmax = tb + 159;
  const u32* brow = &bitsL[(s16 + r)*324];
  const uint4* pB = (const uint4*)Bf;          // frag id

  f32x4 z = {0.f,0.f,0.f,0.f};
  f32x4 G0=z,G1=z,D0=z,D1=z,A0=z,A1=z;
  int cG=0,cD=0,cA=0;

  uint4 B00 = pB[((tb+0)*2)*64 + lane], B01 = pB[((tb+0)*2+1)*64 + lane];
  uint4 B10 = pB[((tb+1)*2)*64 + lane], B11 = pB[((tb+1)*2+1)*64 + lane];
  uint4 B20 = pB[((tb+2)*2)*64 + lane], B21 = pB[((tb+2)*2+1)*64 + lane];
  uint4 B30 = pB[((tb+3)*2)*64 + lane], B31 = pB[((tb+3)*2+1)*64 + lane];

#define MFMA_(AF, B, ACC) __builtin_amdgcn_mfma_f32_16x16x32_bf16((AF).s, (B).s, ACC, 0,0,0)

#define TILEW(J, T) do {                                                       \
    const int t = (T);                                                         \
    const u32 byte = (W4##J >> g8) & 0xFFu;                                    \
    AFrag af;                                                                  \
    af.u[0] = __umul24((byte & 1u)    + (((byte>>1)&1u)<<16), 0x3F80u);        \
    af.u[1] = __umul24(((byte>>2)&1u) + (((byte>>3)&1u)<<16), 0x3F80u);        \
    af.u[2] = __umul24(((byte>>4)&1u) + (((byte>>5)&1u)<<16), 0x3F80u);        \
    af.u[3] = __umul24(((byte>>6)&1u) + (((byte>>7)&1u)<<16), 0x3F80u);        \
    BFrag b0, b1; b0.v = B##J##0; b1.v = B##J##1;                              \
    if (!h0) {                                                                 \
      A0 = MFMA_(af,b0,A0); A1 = MFMA_(af,b1,A1); cA += __popc(byte);          \
    } else if (t == 0) {                                                       \
      G0 = MFMA_(af,b0,G0); G1 = MFMA_(af,b1,G1);                              \
      BFrag e0,e1; e0.v = pB[(321*2)*64 + lane]; e1.v = pB[(321*2+1)*64 + lane]; \
      D0 = MFMA_(af,e0,D0); D1 = MFMA_(af,e1,D1);                              \
      _Pragma("unroll")                                                        \
      for (int jj = 0; jj < 4; ++jj) {                                         \
        const int c0 = g8 + 2*jj, c1 = c0 + 1;                                 \
        const int u0 = (byte>>(2*jj))&1, u1 = (byte>>(2*jj+1))&1;              \
        if (c0 >= 1 && c0 < 26) cG += u0; else if (c0 >= 26) cD += u0;         \
        if (c1 < 26) cG += u1; else cD += u1;                                  \
      }                                                                        \
    } else if (t == 69) {                                                      \
      D0 = MFMA_(af,b0,D0); D1 = MFMA_(af,b1,D1);                              \
      BFrag e0,e1; e0.v = pB[(322*2)*64 + lane]; e1.v = pB[(322*2+1)*64 + lane]; \
      A0 = MFMA_(af,e0,A0); A1 = MFMA_(af,e1,A1);                              \
      _Pragma("unroll")                                                        \
      for (int jj = 0; jj < 4; ++jj) {                                         \
        const int s01 = ((byte>>(2*jj))&1) + ((byte>>(2*jj+1))&1);             \
        if (jj < 2) { if (g == 0) cD += s01; else cA += s01; }                 \
        else cA += s01;                                                        \
      }                                                                        \
    } else if (t < 69) {                                                       \
      D0 = MFMA_(af,b0,D0); D1 = MFMA_(af,b1,D1); cD += __popc(byte);          \
    } else {                                                                   \
      A0 = MFMA_(af,b0,A0); A1 = MFMA_(af,b1,A1); cA += __popc(byte);          \
    }                                                                          \
    int tn = t + 4; if (tn > tmax) tn = tmax;                                  \
    B##J##0 = pB[(tn*2)*64 + lane]; B##J##1 = pB[(tn*2+1)*64 + lane];          \
  } while (0)

  for (int i = 0; i < 40; ++i) {
    const int t0 = tb + 4*i;
    const uint4 W4u = *(const uint4*)&brow[t0];    // ds_read_b128: 4 tiles
    const u32 W40 = W4u.x, W41 = W4u.y, W42 = W4u.z, W43 = W4u.w;
    TILEW(0, t0); TILEW(1, t0+1); TILEW(2, t0+2); TILEW(3, t0+3);
  }
#undef TILEW

  cG += __shfl_xor(cG,16); cG += __shfl_xor(cG,32);
  cD += __shfl_xor(cD,16); cD += __shfl_xor(cD,32);
  cA += __shfl_xor(cA,16); cA += __shfl_xor(cA,32);

#define STOF(ACC0, ACC1, SLOT) do {                                            \
    *(f32x4*)&poutL[SLOT][r][s16 + 4*g]    = ACC0;                             \
    *(f32x4*)&poutL[SLOT][16+r][s16 + 4*g] = ACC1; } while (0)

  if (h0) {
    STOF(G0,G1,0); STOF(D0,D1,1); STOF(A0,A1,2);
    if (lane < 16) {
      poutL[0][32][s16+lane] = (float)cG;
      poutL[1][32][s16+lane] = (float)cD;
      poutL[2][32][s16+lane] = (float)cA;
    }
  } else {
    STOF(A0,A1,3);
    if (lane < 16) poutL[3][32][s16+lane] = (float)cA;
  }
#undef STOF
  __syncthreads();

  // ---- epilogue A: merged counts (with actor tail cols 10240/10241) ----
  if (threadIdx.x < 96) {
    const int seg = threadIdx.x >> 5, row = threadIdx.x & 31;
    float c = poutL[seg][32][row];
    if (seg == 2)
      c += poutL[3][32][row] + (float)sideL[row][1] + (float)sideL[row][2];
    cCnt[seg][row] = c;
  }
  __syncthreads();

  // ---- epilogue B: merge means + tail + divide (in place, slots 0..2) ----
  for (int id = threadIdx.x; id < 3*32*32; id += 256) {
    const int seg = id >> 10;
    const int rem = id & 1023;
    const int d = rem >> 5, row = rem & 31;
    float v = poutL[seg][d][row];
    if (seg == 2) {
      v += poutL[3][d][row];
      v += (float)sideL[row][1] * Wa[d*8030 + 8028]
         + (float)sideL[row][2] * Wa[d*8030 + 8029];
    }
    poutL[seg][d][row] = v / cCnt[seg][row];
  }
  __syncthreads();

  // ---- epilogue C: h1 (8 threads per row, 8 outputs each) ----
  float* hL = (float*)bitsL;                    // [32][64]; bits are dead
  {
    const int row = threadIdx.x >> 3, p = threadIdx.x & 7;
    const int* sd = sideL[row];
    const float* Pr = P + (size_t)sd[0]*64        + p*8;
    const float* Pg = P + (size_t)(6  + sd[3])*64 + p*8;
    const float* Pa = P + (size_t)(8  + sd[4])*64 + p*8;
    const float* Po = P + (size_t)(15 + sd[5])*64 + p*8;
    const float* Pz = P + (size_t)(36 + sd[6])*64 + p*8;
    #pragma unroll
    for (int oo = 0; oo < 8; ++oo) {
      const int o = p*8 + oo;
      float a = b1[o] + ((Pr[oo] + Pg[oo]) + (Pa[oo] + Po[oo])) + Pz[oo];
      const float* w = W1 + o*256;
      #pragma unroll
      for (int d = 0; d < 32; ++d) a = fmaf(poutL[0][d][row], w[32+d], a);
      #pragma unroll
      for (int d = 0; d < 32; ++d) a = fmaf(poutL[1][d][row], w[64+d], a);
      #pragma unroll
      for (int d = 0; d < 32; ++d) a = fmaf(poutL[2][d][row], w[96+d], a);
      hL[row*64 + o] = fmaxf(a, 0.f);
    }
  }
  __syncthreads();

  // ---- epilogue D: h2 + output dot (8 threads per row) ----
  {
    const int row = threadIdx.x >> 3, p = threadIdx.x & 7;
    const float* hr = &hL[row*64];
    float part = 0.f;
    #pragma unroll
    for (int oo = 0; oo < 8; ++oo) {
      const int o2 = p*8 + oo;
      const float* w = W2 + o2*64;
      float acc2 = b2[o2];
      #pragma unroll
      for (int o = 0; o < 64; ++o) acc2 = fmaf(hr[o], w[o], acc2);
      part += fmaxf(acc2, 0.f) * Wout[o2];
    }
    part += __shfl_xor(part, 1);
    part += __shfl_xor(part, 2);
    part += __shfl_xor(part, 4);
    if (p == 0) out[row0 + row] = part + bout[0];
  }
}

// ---------------- launcher ----------------
extern "C" void kernel_launch(void* const* d_in, const int* in_sizes, int n_in,
                              void* d_out, int out_size, void* d_ws, size_t ws_size,
                              hipStream_t stream) {
  (void)in_sizes; (void)n_in; (void)out_size; (void)ws_size;
  const int*   x        = (const int*)  d_in[0];
  const float* emb_rate = (const float*)d_in[1];
  const float* W_genre  = (const float*)d_in[2];
  const float* W_dir    = (const float*)d_in[3];
  const float* W_actor  = (const float*)d_in[4];
  const float* emb_gen  = (const float*)d_in[5];
  const float* emb_age  = (const float*)d_in[6];
  const float* emb_occ  = (const float*)d_in[7];
  const float* emb_area = (const float*)d_in[8];
  const float* W1   = (const float*)d_in[9];
  const float* b1   = (const float*)d_in[10];
  const float* W2   = (const float*)d_in[11];
  const float* b2   = (const float*)d_in[12];
  const float* Wout = (const float*)d_in[13];
  const float* bout = (const float*)d_in[14];
  float* outp = (float*)d_out;

  float* ws = (float*)d_ws;
  u16*   Bf = (u16*)ws;                               // 646 KB, 16B-aligned
  float* P  = (float*)(Bf + BF_U16);

  prep_bf<<<(NSLOT*128 + 255)/256, 256, 0, stream>>>(W_genre, W_dir, W_actor, Bf);
  prep_p<<<(PTAB_F + 255)/256, 256, 0, stream>>>(emb_rate, emb_gen, emb_age, emb_occ,
                                                 emb_area, W1, P);

  fusedK<<<NROW/32, 256, 0, stream>>>(x, Bf, P, W1, b1, W2, b2, Wout, bout,
                                      W_actor, outp);
}